// Round 1
// baseline (142.831 us; speedup 1.0000x reference)
//
#include <hip/hip_runtime.h>

// ROI max pooling, matching the JAX reference:
//   img:  (1, 200, 200, 512) fp32, NHWC
//   rois: (1, 128, 4) fp32 as (x, y, w, h) in feature-map pixels
//   pool: 7
// out: (1, 128, 7, 7, 512) fp32
//
// Bin boundaries replicate  int(x + k*(w/P))  in strict IEEE fp32
// (separate div/mul/add, no FMA contraction) so the integer pixel ranges
// match the reference exactly; the max over identical pixel sets is then
// bitwise identical.
//
// R3: latency-exposure fix — 4 independent row accumulator chains
// (halves memory round trips per block vs 2-row version: avg bin is
// ~5 rows, so ceil(rows/4)+rem instead of ceil(rows/2) serialized
// load->waitcnt->max phases), x-unroll 2 keeps 8 loads in flight even
// for 1-2 px wide bins. Output uses nontemporal stores (never re-read;
// preserve LLC residency for the image, which serves ~200 MB of
// cross-ROI reuse).

#define IMG_H 200
#define IMG_W 200
#define IMG_C 512
#define C4 (IMG_C / 4)   // 128 float4 slots per pixel
#define POOL 7
#define NROI 128

typedef float f4v __attribute__((ext_vector_type(4)));

__device__ __forceinline__ float4 max4(float4 a, float4 b) {
    return make_float4(fmaxf(a.x, b.x), fmaxf(a.y, b.y),
                       fmaxf(a.z, b.z), fmaxf(a.w, b.w));
}

__global__ __launch_bounds__(128) void roi_pool_kernel(
    const float* __restrict__ img,
    const float* __restrict__ rois,
    float* __restrict__ out)
{
    const int bin = blockIdx.x % (POOL * POOL);
    const int roi = blockIdx.x / (POOL * POOL);
    const int jy = bin / POOL;
    const int ix = bin % POOL;

    const float rx = rois[roi * 4 + 0];
    const float ry = rois[roi * 4 + 1];
    const float rw = rois[roi * 4 + 2];
    const float rh = rois[roi * 4 + 3];

    // Strict fp32, no contraction: s = w/P; b[k] = int(x + k*s)
    const float sx = __fdiv_rn(rw, 7.0f);
    const float sy = __fdiv_rn(rh, 7.0f);
    const int x1 = (int)__fadd_rn(rx, __fmul_rn((float)ix,       sx));
    const int x2 = (int)__fadd_rn(rx, __fmul_rn((float)(ix + 1), sx));
    const int y1 = (int)__fadd_rn(ry, __fmul_rn((float)jy,       sy));
    const int y2 = (int)__fadd_rn(ry, __fmul_rn((float)(jy + 1), sy));

    const int c4 = threadIdx.x;            // 0..127, one float4 of channels
    const float4* __restrict__ img4 = (const float4*)img;

    const float4 NEG = make_float4(-INFINITY, -INFINITY, -INFINITY, -INFINITY);
    float4 m0 = NEG, m1 = NEG, m2 = NEG, m3 = NEG;

    int y = y1;
    int rem = y2 - y1;

    // 4 rows at a time: 4 independent load+max chains -> 8 loads in
    // flight per unrolled x-iteration regardless of bin width.
    for (; rem >= 4; rem -= 4, y += 4) {
        const float4* __restrict__ r0 = img4 + ((size_t)y * IMG_W) * C4 + c4;
        const float4* __restrict__ r1 = r0 + (size_t)IMG_W * C4;
        const float4* __restrict__ r2 = r1 + (size_t)IMG_W * C4;
        const float4* __restrict__ r3 = r2 + (size_t)IMG_W * C4;
        #pragma unroll 2
        for (int x = x1; x < x2; ++x) {
            m0 = max4(m0, r0[(size_t)x * C4]);
            m1 = max4(m1, r1[(size_t)x * C4]);
            m2 = max4(m2, r2[(size_t)x * C4]);
            m3 = max4(m3, r3[(size_t)x * C4]);
        }
    }
    if (rem >= 2) {
        const float4* __restrict__ r0 = img4 + ((size_t)y * IMG_W) * C4 + c4;
        const float4* __restrict__ r1 = r0 + (size_t)IMG_W * C4;
        #pragma unroll 4
        for (int x = x1; x < x2; ++x) {
            m0 = max4(m0, r0[(size_t)x * C4]);
            m1 = max4(m1, r1[(size_t)x * C4]);
        }
        y += 2; rem -= 2;
    }
    if (rem) {
        const float4* __restrict__ r0 = img4 + ((size_t)y * IMG_W) * C4 + c4;
        #pragma unroll 4
        for (int x = x1; x < x2; ++x)
            m0 = max4(m0, r0[(size_t)x * C4]);
    }

    float4 m = max4(max4(m0, m1), max4(m2, m3));

    float4* __restrict__ out4 = (float4*)out;
    f4v* __restrict__ dst =
        (f4v*)&out4[((size_t)(roi * POOL + jy) * POOL + ix) * C4 + c4];
    __builtin_nontemporal_store(*(const f4v*)&m, dst);
}

extern "C" void kernel_launch(void* const* d_in, const int* in_sizes, int n_in,
                              void* d_out, int out_size, void* d_ws, size_t ws_size,
                              hipStream_t stream) {
    (void)in_sizes; (void)n_in; (void)d_ws; (void)ws_size; (void)out_size;
    const float* img  = (const float*)d_in[0];
    const float* rois = (const float*)d_in[1];
    // d_in[2] is pool_size (=7), hardcoded.
    float* out = (float*)d_out;

    dim3 grid(NROI * POOL * POOL);
    dim3 block(128);
    roi_pool_kernel<<<grid, block, 0, stream>>>(img, rois, out);
}

// Round 2
// 140.206 us; speedup vs baseline: 1.0187x; 1.0187x over previous
//
#include <hip/hip_runtime.h>

// ROI max pooling, matching the JAX reference:
//   img:  (1, 200, 200, 512) fp32, NHWC
//   rois: (1, 128, 4) fp32 as (x, y, w, h) in feature-map pixels
//   pool: 7
// out: (1, 128, 7, 7, 512) fp32
//
// Bin boundaries replicate  int(x + k*(w/P))  in strict IEEE fp32
// (separate div/mul/add, no FMA contraction) so the integer pixel ranges
// match the reference exactly; the max over identical pixel sets is then
// bitwise identical.
//
// R4: occupancy/imbalance fix. R3 post-mortem showed VGPR=36 (compiler
// refuses >4 loads in flight per wave) and OccupancyPercent=50% from
// 12544 waves = 1.53 machine fills with ~80x per-block duration variance.
// New decomposition: 512-thread blocks = 128 c4-channels x 4 pixel-lanes;
// each lane strides the linearized bin pixel list, LDS max-reduce at the
// end. Same logical loads (bitwise-identical max), but 50176 short waves
// -> 6.1 machine fills, 4x lower block-duration variance, smooth tail.

#define IMG_H 200
#define IMG_W 200
#define IMG_C 512
#define C4 (IMG_C / 4)   // 128 float4 slots per pixel
#define POOL 7
#define NROI 128
#define PLANES 4         // pixel-lanes per block

typedef float f4v __attribute__((ext_vector_type(4)));

__device__ __forceinline__ float4 max4(float4 a, float4 b) {
    return make_float4(fmaxf(a.x, b.x), fmaxf(a.y, b.y),
                       fmaxf(a.z, b.z), fmaxf(a.w, b.w));
}

__global__ __launch_bounds__(PLANES * 128, 8) void roi_pool_kernel(
    const float* __restrict__ img,
    const float* __restrict__ rois,
    float* __restrict__ out)
{
    const int bin = blockIdx.x % (POOL * POOL);
    const int roi = blockIdx.x / (POOL * POOL);
    const int jy = bin / POOL;
    const int ix = bin % POOL;

    const float rx = rois[roi * 4 + 0];
    const float ry = rois[roi * 4 + 1];
    const float rw = rois[roi * 4 + 2];
    const float rh = rois[roi * 4 + 3];

    // Strict fp32, no contraction: s = w/P; b[k] = int(x + k*s)
    const float sx = __fdiv_rn(rw, 7.0f);
    const float sy = __fdiv_rn(rh, 7.0f);
    const int x1 = (int)__fadd_rn(rx, __fmul_rn((float)ix,       sx));
    const int x2 = (int)__fadd_rn(rx, __fmul_rn((float)(ix + 1), sx));
    const int y1 = (int)__fadd_rn(ry, __fmul_rn((float)jy,       sy));
    const int y2 = (int)__fadd_rn(ry, __fmul_rn((float)(jy + 1), sy));

    const int c4 = threadIdx.x & 127;       // channel quad
    const int p  = threadIdx.x >> 7;        // pixel-lane 0..3
    const float4* __restrict__ img4 = (const float4*)img;

    const int bw = x2 - x1;                 // >= 1 by problem construction
    const int bh = y2 - y1;
    const int area = bw * bh;

    const float4 NEG = make_float4(-INFINITY, -INFINITY, -INFINITY, -INFINITY);
    float4 m = NEG;

    // Lane p handles linearized bin pixels p, p+4, p+8, ... (row-major in bin).
    int dx = p, dy = 0;
    while (dx >= bw) { dx -= bw; ++dy; }    // p<4, cheap init
    #pragma unroll 2
    for (int i = p; i < area; i += PLANES) {
        const size_t px = (size_t)(y1 + dy) * IMG_W + (size_t)(x1 + dx);
        m = max4(m, img4[px * C4 + c4]);
        dx += PLANES;
        while (dx >= bw) { dx -= bw; ++dy; }
    }

    // Cross-lane (p) reduction via LDS. Lanes with no pixels hold -INF
    // (identity for max); lane 0 always has >=1 pixel.
    __shared__ float4 red[PLANES - 1][C4];
    if (p > 0) red[p - 1][c4] = m;
    __syncthreads();
    if (p == 0) {
        m = max4(m, red[0][c4]);
        m = max4(m, red[1][c4]);
        m = max4(m, red[2][c4]);

        float4* __restrict__ out4 = (float4*)out;
        f4v* __restrict__ dst =
            (f4v*)&out4[((size_t)(roi * POOL + jy) * POOL + ix) * C4 + c4];
        __builtin_nontemporal_store(*(const f4v*)&m, dst);
    }
}

extern "C" void kernel_launch(void* const* d_in, const int* in_sizes, int n_in,
                              void* d_out, int out_size, void* d_ws, size_t ws_size,
                              hipStream_t stream) {
    (void)in_sizes; (void)n_in; (void)d_ws; (void)ws_size; (void)out_size;
    const float* img  = (const float*)d_in[0];
    const float* rois = (const float*)d_in[1];
    // d_in[2] is pool_size (=7), hardcoded.
    float* out = (float*)d_out;

    dim3 grid(NROI * POOL * POOL);
    dim3 block(PLANES * 128);
    roi_pool_kernel<<<grid, block, 0, stream>>>(img, rois, out);
}